// Round 14
// baseline (320.993 us; speedup 1.0000x reference)
//
#include <hip/hip_runtime.h>

// ---------------------------------------------------------------------------
// MultiHeadAttention: B=8, S=1024, D=1024, H=16, dh=64
// outputs: out [8,1024,1024] f32, qk [8,16,1024,1024] f32 (concat in d_out)
// ---------------------------------------------------------------------------

typedef unsigned short u16;
typedef unsigned int   u32;
typedef unsigned long long u64;
typedef __attribute__((ext_vector_type(8)))  __bf16 bf16x8;
typedef __attribute__((ext_vector_type(4)))  float  f32x4;
typedef __attribute__((ext_vector_type(16))) float  f32x16;

__device__ __forceinline__ u16 f2bf(float f) {
  u32 u = __float_as_uint(f);
  u += 0x7FFFu + ((u >> 16) & 1u);   // round-to-nearest-even
  return (u16)(u >> 16);
}
__device__ __forceinline__ float bf2f(u16 v) {
  return __uint_as_float(((u32)v) << 16);
}
// HW packed f32->bf16 (RNE), 1 instr; src0 -> low half, src1 -> high half
__device__ __forceinline__ u32 cvtpk(float lo, float hi) {
  u32 r;
  asm("v_cvt_pk_bf16_f32 %0, %1, %2" : "=v"(r) : "v"(lo), "v"(hi));
  return r;
}
__device__ __forceinline__ f32x4 mfma16(bf16x8 a, bf16x8 b, f32x4 c) {
  return __builtin_amdgcn_mfma_f32_16x16x32_bf16(a, b, c, 0, 0, 0);
}
__device__ __forceinline__ f32x16 mfma32(bf16x8 a, bf16x8 b, f32x16 c) {
  return __builtin_amdgcn_mfma_f32_32x32x16_bf16(a, b, c, 0, 0, 0);
}
typedef __attribute__((address_space(3))) u32 lds_u32;
typedef const __attribute__((address_space(1))) u32 glb_u32;
__device__ __forceinline__ void gld_lds16(u16* lds, const u16* g) {
  __builtin_amdgcn_global_load_lds((glb_u32*)g, (lds_u32*)lds, 16, 0, 0);
}
__device__ __forceinline__ bf16x8 ld_bf8(const u16* p) {
  return *(const bf16x8*)p;
}

// ---------------------------------------------------------------------------
// fused f32 -> bf16 conversion for x + 4 weight matrices (8 elems/thread)
// ---------------------------------------------------------------------------
__global__ __launch_bounds__(256) void cvt_all(
    const float* __restrict__ x,
    const float* __restrict__ Wq, const float* __restrict__ Wk,
    const float* __restrict__ Wv, const float* __restrict__ Wo,
    u16* __restrict__ xb, u16* __restrict__ Wqb, u16* __restrict__ Wkb,
    u16* __restrict__ Wvb, u16* __restrict__ Wob) {
  const size_t i = (size_t)(blockIdx.x * 256 + threadIdx.x) * 8;
  const float* s; u16* d; size_t off;
  if      (i <  8388608) { s = x;  d = xb;  off = i; }
  else if (i <  9437184) { s = Wq; d = Wqb; off = i -  8388608; }
  else if (i < 10485760) { s = Wk; d = Wkb; off = i -  9437184; }
  else if (i < 11534336) { s = Wv; d = Wvb; off = i - 10485760; }
  else                   { s = Wo; d = Wob; off = i - 11534336; }
  const float4* sp = (const float4*)(s + off);
  float4 a = sp[0], b = sp[1];
  u16 r[8];
  r[0] = f2bf(a.x); r[1] = f2bf(a.y); r[2] = f2bf(a.z); r[3] = f2bf(a.w);
  r[4] = f2bf(b.x); r[5] = f2bf(b.y); r[6] = f2bf(b.z); r[7] = f2bf(b.w);
  *(uint4*)(d + off) = *(const uint4*)r;
}

// ---------------------------------------------------------------------------
// mask [S][S] f32 -> maskT [k][q] bf16 (transposed), 32x32 LDS tiles
// (KEPT: the transpose is semantically required — R9 dropped it and broke.)
// ---------------------------------------------------------------------------
__global__ __launch_bounds__(256) void trans_mask(
    const float* __restrict__ m, u16* __restrict__ mt) {
  __shared__ u16 L[32][33];
  const int x = threadIdx.x & 31, y4 = threadIdx.x >> 5;   // y4: 0..7
  const int r0 = blockIdx.y * 32, c0 = blockIdx.x * 32;
#pragma unroll
  for (int j = 0; j < 4; ++j) {
    const int r = y4 * 4 + j;
    L[x][r] = f2bf(m[(r0 + r) * 1024 + c0 + x]);
  }
  __syncthreads();
#pragma unroll
  for (int j = 0; j < 4; ++j) {
    const int rr = y4 * 4 + j;
    mt[(c0 + rr) * 1024 + r0 + x] = L[rr][x];
  }
}

// ---------------------------------------------------------------------------
// maskT [k][q] -> maskP [c][hi][q][r:16]  (MFMA-fragment-ordered mask)
// ---------------------------------------------------------------------------
__global__ __launch_bounds__(256) void mask_pack(
    const u16* __restrict__ mt, u16* __restrict__ mp) {
  const int id = blockIdx.x * 256 + threadIdx.x;   // 65536 threads
  const int q  = id & 1023;
  const int hi = (id >> 10) & 1;
  const int c  = id >> 11;
  u16 r0[8], r1[8];
#pragma unroll
  for (int r = 0; r < 8; ++r)
    r0[r] = mt[(32 * c + (r & 3) + 8 * (r >> 2) + 4 * hi) * 1024 + q];
#pragma unroll
  for (int r = 8; r < 16; ++r)
    r1[r - 8] = mt[(32 * c + (r & 3) + 8 * (r >> 2) + 4 * hi) * 1024 + q];
  u16* dst = mp + ((size_t)((c * 2 + hi) * 1024 + q)) * 16;
  *(uint4*)dst       = *(const uint4*)r0;
  *(uint4*)(dst + 8) = *(const uint4*)r1;
}

// ---------------------------------------------------------------------------
// Projection GEMM: C[8192, 3072] = xb @ [Wq;Wk;Wv]^T  (K=1024, BK=32, 128x128)
// 2-phase pipelined (double-buffered LDS, stage-next before compute).
// Epilogue stores NON-TEMPORAL: Qt2/Kt2/V2 only re-read by the NEXT kernel
// (cross-XCD -> effectively L3 anyway); keeping the 48 MB write stream out
// of L2 preserves the A/B panel working set (R12's proven mechanism).
// ---------------------------------------------------------------------------
__global__ __launch_bounds__(256) void proj_gemm(
    const u16* __restrict__ xb,
    const u16* __restrict__ Wqb, const u16* __restrict__ Wkb,
    const u16* __restrict__ Wvb,
    const float* __restrict__ bq, const float* __restrict__ bv,
    u16* __restrict__ Qt2, u16* __restrict__ Kt2, u16* __restrict__ V2) {
  __shared__ u16 As[2][128][32];
  __shared__ u16 Bs[2][128][32];
  const int tid  = threadIdx.x;
  const int lane = tid & 63;
  const int wid  = tid >> 6;
  const int c15  = lane & 15, c4 = lane >> 4;
  const int m0   = blockIdx.x * 128;
  const int nv0  = blockIdx.y * 128;          // virtual col in [0,3072)
  const int region = nv0 >> 10;               // 0=q 1=k 2=v (1024-aligned)
  const int nl0  = nv0 & 1023;
  const u16* Wsrc = (region == 0) ? Wqb : (region == 1) ? Wkb : Wvb;
  const int wrow = wid >> 1, wcol = wid & 1;
  const int srow = lane >> 2, scol = (lane & 3) * 8;

  const u16* aptr = xb   + (m0  + srow) * 1024 + scol;
  const u16* bptr = Wsrc + (nl0 + srow) * 1024 + scol;

  f32x4 acc[4][4] = {};

#pragma unroll
  for (int j = 0; j < 2; ++j) {
    const int r = 64 * j + 16 * wid;
    gld_lds16(&As[0][r][0], aptr + r * 1024);
    gld_lds16(&Bs[0][r][0], bptr + r * 1024);
  }
  __syncthreads();

  int cur = 0;
  for (int k0 = 0; k0 < 1024; k0 += 32) {
    if (k0 + 32 < 1024) {
      const int nxt = cur ^ 1;
#pragma unroll
      for (int j = 0; j < 2; ++j) {
        const int r = 64 * j + 16 * wid;
        gld_lds16(&As[nxt][r][0], aptr + r * 1024 + k0 + 32);
        gld_lds16(&Bs[nxt][r][0], bptr + r * 1024 + k0 + 32);
      }
    }
    bf16x8 af[4], bfr[4];
#pragma unroll
    for (int a = 0; a < 4; ++a) af[a]  = ld_bf8(&As[cur][64 * wrow + 16 * a + c15][8 * c4]);
#pragma unroll
    for (int b = 0; b < 4; ++b) bfr[b] = ld_bf8(&Bs[cur][64 * wcol + 16 * b + c15][8 * c4]);
#pragma unroll
    for (int a = 0; a < 4; ++a)
#pragma unroll
      for (int b = 0; b < 4; ++b)
        acc[a][b] = mfma16(af[a], bfr[b], acc[a][b]);
    __syncthreads();
    cur ^= 1;
  }

  const float kSc = 0.35355339059327373f;  // 64^-0.25
#pragma unroll
  for (int a = 0; a < 4; ++a) {
    const int mg = m0 + 64 * wrow + 16 * a + 4 * c4;
    const int bb = mg >> 10;                 // batch
    const int sl = mg & 1023;                // seq pos (mg%4==0, j adds 0..3)
#pragma unroll
    for (int b = 0; b < 4; ++b) {
      const int nl = 64 * wcol + 16 * b + c15;
      const int nv = nv0 + nl;
      if (region == 0) {
        const int n = nv;                    // h*64 + d
        const float bias = bq[n];
        u16* qp = Qt2 + (((bb * 16 + (n >> 6)) * 8 + ((n >> 3) & 7)) * 1024 + sl) * 8 + (n & 7);
#pragma unroll
        for (int j = 0; j < 4; ++j)
          __builtin_nontemporal_store(f2bf((acc[a][b][j] + bias) * kSc), qp + j * 8);
      } else if (region == 1) {
        const int n = nv - 1024;             // h*64 + d
        u16* kp = Kt2 + (((bb * 16 + (n >> 6)) * 8 + ((n >> 3) & 7)) * 1024 + sl) * 8 + (n & 7);
#pragma unroll
        for (int j = 0; j < 4; ++j)
          __builtin_nontemporal_store(f2bf(acc[a][b][j] * kSc), kp + j * 8);
      } else {
        const int n = nv - 2048;             // h*64 + d
        const float bias = bv[n];
        u16* vp = V2 + (((bb * 16 + (n >> 6)) * 128 + (sl >> 3)) * 64 + (n & 63)) * 8 + (sl & 7);
        u16 p[4];
#pragma unroll
        for (int j = 0; j < 4; ++j) p[j] = f2bf(acc[a][b][j] + bias);
        u64 pk; __builtin_memcpy(&pk, p, 8);
        __builtin_nontemporal_store(pk, (u64*)vp);   // native u64: builtin-legal
      }
    }
  }
}

// ---------------------------------------------------------------------------
// Attention v6 (unchanged from R12): single-pass online softmax (defer-max),
// swapped QK^T, loads issued before qk stores (vmcnt decoupling),
// NON-TEMPORAL qk stores (L2-thrash fix), cvt_pk P-pack + max3 + dual-l.
// ---------------------------------------------------------------------------
__global__ __launch_bounds__(256) void attn_v6(
    const u16* __restrict__ Qt2, const u16* __restrict__ Kt2,
    const u16* __restrict__ V2, const u16* __restrict__ maskP,
    float* __restrict__ qk, u16* __restrict__ WV) {
  __shared__ float Tb[4][32 * 34];
  __shared__ float invl[4][32];
  __shared__ float factw[4][32];
  const int tid  = threadIdx.x;
  const int lane = tid & 63;
  const int w    = tid >> 6;
  const int r31  = lane & 31, hi = lane >> 5;
  const int h = blockIdx.y, b = blockIdx.z;
  const int bh  = b * 16 + h;
  const int q0  = blockIdx.x * 128 + w * 32;
  const int bs0 = b * 1024;

  const u16* qbase = Qt2 + (size_t)bh * 65536;
  const u16* kbase = Kt2 + (size_t)bh * 65536;
  const u16* vbase = V2  + (size_t)bh * 65536;
  float* Tw = Tb[w];
  float* qkbase = qk + ((size_t)bh * 1024 + q0) * 1024;

  bf16x8 qf[4];
#pragma unroll
  for (int kk = 0; kk < 4; ++kk)
    qf[kk] = ld_bf8(qbase + ((2 * kk + hi) * 1024 + q0 + r31) * 8);

  const u16* mrow = maskP + ((size_t)(hi * 1024 + q0 + r31)) * 16;

  float m_run = -3e38f;
  float l0 = 0.f, l1 = 0.f;
  f32x16 oa0 = {}, oa1 = {};

  bf16x8 kc[4];
#pragma unroll
  for (int kk = 0; kk < 4; ++kk)
    kc[kk] = ld_bf8(kbase + ((2 * kk + hi) * 1024 + r31) * 8);
  bf16x8 mc0 = ld_bf8(mrow);
  bf16x8 mc1 = ld_bf8(mrow + 8);

  for (int c = 0; c < 32; ++c) {
    // ---- loads consumed this iter / next iter: ISSUED BEFORE qk stores ----
    bf16x8 vf[4];
#pragma unroll
    for (int kk = 0; kk < 2; ++kk) {
      const int sb = 4 * c + 2 * kk + hi;
      vf[2 * kk]     = ld_bf8(vbase + (sb * 64 + r31) * 8);
      vf[2 * kk + 1] = ld_bf8(vbase + (sb * 64 + 32 + r31) * 8);
    }
    const int cn = (c < 31) ? c + 1 : 31;
    bf16x8 kn[4];
#pragma unroll
    for (int kk = 0; kk < 4; ++kk)
      kn[kk] = ld_bf8(kbase + ((2 * kk + hi) * 1024 + 32 * cn + r31) * 8);
    bf16x8 mn0 = ld_bf8(mrow + (size_t)cn * 32768);
    bf16x8 mn1 = ld_bf8(mrow + (size_t)cn * 32768 + 8);

    // ---- QK^T tile: S[32k][32q], lane col = q ----
    f32x16 acc = {};
#pragma unroll
    for (int kk = 0; kk < 4; ++kk)
      acc = mfma32(kc[kk], qf[kk], acc);

    float v[16];
    const u16* mcu0 = (const u16*)&mc0;
    const u16* mcu1 = (const u16*)&mc1;
#pragma unroll
    for (int r = 0; r < 16; ++r)
      v[r] = acc[r] + bf2f(r < 8 ? mcu0[r] : mcu1[r - 8]);
    // max3-fusable reduction tree
    float t0 = fmaxf(fmaxf(v[0], v[1]),  v[2]);
    float t1 = fmaxf(fmaxf(v[3], v[4]),  v[5]);
    float t2 = fmaxf(fmaxf(v[6], v[7]),  v[8]);
    float t3 = fmaxf(fmaxf(v[9], v[10]), v[11]);
    float t4 = fmaxf(fmaxf(v[12], v[13]), v[14]);
    float mloc = fmaxf(fmaxf(fmaxf(fmaxf(t0, t1), t2), fmaxf(t3, t4)), v[15]);
    mloc = fmaxf(mloc, __shfl_xor(mloc, 32));

    // ---- park S in Tw (float2-packed; kr = 8g+4hi+j) ----
#pragma unroll
    for (int g = 0; g < 4; ++g) {
      float2 w0; w0.x = v[4 * g];     w0.y = v[4 * g + 1];
      float2 w1; w1.x = v[4 * g + 2]; w1.y = v[4 * g + 3];
      *(float2*)&Tw[r31 * 34 + 8 * g + 4 * hi]     = w0;
      *(float2*)&Tw[r31 * 34 + 8 * g + 4 * hi + 2] = w1;
    }

    // ---- defer-max rescale (rare) ----
    if (!__all(mloc <= m_run + 8.f)) {
      const float m_new = fmaxf(m_run, mloc);
      const float f = __expf(m_run - m_new);
      l0 *= f; l1 *= f;
      if (hi == 0) factw[w][r31] = f;
      asm volatile("s_waitcnt lgkmcnt(0)" ::: "memory");
#pragma unroll
      for (int r = 0; r < 16; ++r) {
        const float fr_ = factw[w][(r & 3) + 8 * (r >> 2) + 4 * hi];
        oa0[r] *= fr_;
        oa1[r] *= fr_;
      }
      m_run = m_new;
    }

    // ---- readback transposed rows -> 128B-coalesced NT qk stores ----
#pragma unroll
    for (int qi = 0; qi < 4; ++qi) {
      const int qq = 8 * qi + (lane >> 3);
      const int jj = (lane & 7) * 4;
      float2 u0 = *(const float2*)&Tw[qq * 34 + jj];
      float2 u1 = *(const float2*)&Tw[qq * 34 + jj + 2];
      f32x4 o; o[0] = u0.x; o[1] = u0.y; o[2] = u1.x; o[3] = u1.y;
      __builtin_nontemporal_store(o, (f32x4*)&qkbase[qq * 1024 + 32 * c + jj]);
    }

    // ---- P = exp(S - m_run), l accumulate (2 chains) ----
#pragma unroll
    for (int r = 0; r < 16; ++r)
      v[r] = __expf(v[r] - m_run);
#pragma unroll
    for (int r = 0; r < 8; ++r) { l0 += v[2 * r]; l1 += v[2 * r + 1]; }

    // ---- PV: build A-frags via cvt_pk + half-exchange ----
#pragma unroll
    for (int kk = 0; kk < 2; ++kk) {
      const float* pp = v + 8 * kk;
      const u32 a0 = cvtpk(pp[0], pp[1]), a1 = cvtpk(pp[2], pp[3]);
      const u32 b0 = cvtpk(pp[4], pp[5]), b1 = cvtpk(pp[6], pp[7]);
      const u32 s0 = hi ? a0 : b0, s1 = hi ? a1 : b1;
      const u32 t0x = __shfl_xor(s0, 32), t1x = __shfl_xor(s1, 32);
      union { u32 u[4]; bf16x8 v; } fr;
      fr.u[0] = hi ? t0x : a0;  fr.u[1] = hi ? t1x : a1;
      fr.u[2] = hi ? b0 : t0x;  fr.u[3] = hi ? b1 : t1x;
      oa0 = mfma32(fr.v, vf[2 * kk],     oa0);
      oa1 = mfma32(fr.v, vf[2 * kk + 1], oa1);
    }

#pragma unroll
    for (int kk = 0; kk < 4; ++kk) kc[kk] = kn[kk];
    mc0 = mn0; mc1 = mn1;
  }

  float l = l0 + l1;
  l += __shfl_xor(l, 32);
  if (hi == 0) invl[w][r31] = 1.0f / l;
  asm volatile("s_waitcnt lgkmcnt(0)" ::: "memory");
#pragma unroll
  for (int r = 0; r < 16; ++r) {
    const int q = (r & 3) + 8 * (r >> 2) + 4 * hi;
    const float iv = invl[w][q];
    u16* wp = WV + (size_t)(bs0 + q0 + q) * 1024 + h * 64;
    wp[r31]      = f2bf(oa0[r] * iv);
    wp[32 + r31] = f2bf(oa1[r] * iv);
  }
}

// ---------------------------------------------------------------------------
// Output GEMM: out[8192,1024] = WV @ Wo^T + bo  (f32 out), 2-phase pipelined.
// outp stores non-temporal (never re-read).
// ---------------------------------------------------------------------------
__global__ __launch_bounds__(256) void out_gemm(
    const u16* __restrict__ Ab, const u16* __restrict__ Wb,
    const float* __restrict__ bias, float* __restrict__ outp) {
  __shared__ u16 As[2][128][32];
  __shared__ u16 Bs[2][128][32];
  const int tid  = threadIdx.x;
  const int lane = tid & 63;
  const int wid  = tid >> 6;
  const int c15  = lane & 15, c4 = lane >> 4;
  const int m0   = blockIdx.x * 128;
  const int n0   = blockIdx.y * 128;
  const int wrow = wid >> 1, wcol = wid & 1;
  const int srow = lane >> 2, scol = (lane & 3) * 8;

  const u16* aptr = Ab + (m0 + srow) * 1024 + scol;
  const u16* bptr = Wb + (n0 + srow) * 1024 + scol;

  f32x4 acc[4][4] = {};

#pragma unroll
  for (int j = 0; j < 2; ++j) {
    const int r = 64 * j + 16 * wid;
    gld_lds16(&As[0][r][0], aptr + r * 1024);
    gld_lds16(&Bs[0][r][0], bptr + r * 1024);
  }
  __syncthreads();

  int cur = 0;
  for (int k0 = 0; k0 < 1024; k0 += 32) {
    if (k0 + 32 < 1024) {
      const int nxt = cur ^ 1;
#pragma unroll
      for (int j = 0; j < 2; ++j) {
        const int r = 64 * j + 16 * wid;
        gld_lds16(&As[nxt][r][0], aptr + r * 1024 + k0 + 32);
        gld_lds16(&Bs[nxt][r][0], bptr + r * 1024 + k0 + 32);
      }
    }
    bf16x8 af[4], bfr[4];
#pragma unroll
    for (int a = 0; a < 4; ++a) af[a]  = ld_bf8(&As[cur][64 * wrow + 16 * a + c15][8 * c4]);
#pragma unroll
    for (int b = 0; b < 4; ++b) bfr[b] = ld_bf8(&Bs[cur][64 * wcol + 16 * b + c15][8 * c4]);
#pragma unroll
    for (int a = 0; a < 4; ++a)
#pragma unroll
      for (int b = 0; b < 4; ++b)
        acc[a][b] = mfma16(af[a], bfr[b], acc[a][b]);
    __syncthreads();
    cur ^= 1;
  }

#pragma unroll
  for (int a = 0; a < 4; ++a) {
    const int mg = m0 + 64 * wrow + 16 * a + 4 * c4;
#pragma unroll
    for (int b = 0; b < 4; ++b) {
      const int ng = n0 + 64 * wcol + 16 * b + c15;
      const float bi = bias[ng];
#pragma unroll
      for (int j = 0; j < 4; ++j)
        __builtin_nontemporal_store(acc[a][b][j] + bi,
                                    &outp[(size_t)(mg + j) * 1024 + ng]);
    }
  }
}

// ---------------------------------------------------------------------------
extern "C" void kernel_launch(void* const* d_in, const int* in_sizes, int n_in,
                              void* d_out, int out_size, void* d_ws, size_t ws_size,
                              hipStream_t stream) {
  const float* x    = (const float*)d_in[0];
  const float* mask = (const float*)d_in[1];
  const float* Wq   = (const float*)d_in[2];
  const float* bq   = (const float*)d_in[3];
  const float* Wk   = (const float*)d_in[4];
  const float* Wv   = (const float*)d_in[5];
  const float* bv   = (const float*)d_in[6];
  const float* Wo   = (const float*)d_in[7];
  const float* bo   = (const float*)d_in[8];

  float* outp = (float*)d_out;
  float* qk   = outp + 8 * 1024 * 1024;      // second output

  // workspace (bf16 elements): ~94 MB total
  u16* ws    = (u16*)d_ws;
  u16* xb    = ws;                    // 8388608
  u16* Wqb   = xb  + 8388608;         // 1048576
  u16* Wkb   = Wqb + 1048576;
  u16* Wvb   = Wkb + 1048576;
  u16* Wob   = Wvb + 1048576;
  u16* Qt2   = Wob + 1048576;         // 8388608 ([bh][d>>3][s][d&7], scaled+bias)
  u16* Kt2   = Qt2 + 8388608;         // 8388608 ([bh][d>>3][s][d&7], scaled)
  u16* V2    = Kt2 + 8388608;         // 8388608 ([bh][s>>3][d][s&7])
  u16* WV    = V2  + 8388608;         // 8388608
  u16* maskT = WV  + 8388608;         // 1048576 (bf16, transposed [k][q])
  u16* maskP = maskT + 1048576;       // 1048576 (fragment-ordered [c][hi][q][r])

  cvt_all<<<6144, 256, 0, stream>>>(x, Wq, Wk, Wv, Wo, xb, Wqb, Wkb, Wvb, Wob);
  trans_mask<<<dim3(32, 32), 256, 0, stream>>>(mask, maskT);
  mask_pack<<<256, 256, 0, stream>>>(maskT, maskP);

  proj_gemm<<<dim3(64, 24), 256, 0, stream>>>(xb, Wqb, Wkb, Wvb, bq, bv, Qt2, Kt2, V2);
  attn_v6<<<dim3(8, 16, 8), 256, 0, stream>>>(Qt2, Kt2, V2, maskP, qk, WV);
  out_gemm<<<dim3(64, 8), 256, 0, stream>>>(WV, Wob, bo, outp);
}

// Round 15
// 263.458 us; speedup vs baseline: 1.2184x; 1.2184x over previous
//
#include <hip/hip_runtime.h>

// ---------------------------------------------------------------------------
// MultiHeadAttention: B=8, S=1024, D=1024, H=16, dh=64
// outputs: out [8,1024,1024] f32, qk [8,16,1024,1024] f32 (concat in d_out)
//
// Final configuration (R12-proven):
//  - attn: NT qk stores (full 128B segments -> bypass L2 thrash)  [R12 win]
//  - out_gemm: NT outp stores (coalesced f32)                     [R12 win]
//  - proj: REGULAR epilogue stores (scattered 2B/8B need L2 write-
//    coalescing; NT here amplifies write transactions — R14 regression)
// ---------------------------------------------------------------------------

typedef unsigned short u16;
typedef unsigned int   u32;
typedef __attribute__((ext_vector_type(8)))  __bf16 bf16x8;
typedef __attribute__((ext_vector_type(4)))  float  f32x4;
typedef __attribute__((ext_vector_type(16))) float  f32x16;

__device__ __forceinline__ u16 f2bf(float f) {
  u32 u = __float_as_uint(f);
  u += 0x7FFFu + ((u >> 16) & 1u);   // round-to-nearest-even
  return (u16)(u >> 16);
}
__device__ __forceinline__ float bf2f(u16 v) {
  return __uint_as_float(((u32)v) << 16);
}
// HW packed f32->bf16 (RNE), 1 instr; src0 -> low half, src1 -> high half
__device__ __forceinline__ u32 cvtpk(float lo, float hi) {
  u32 r;
  asm("v_cvt_pk_bf16_f32 %0, %1, %2" : "=v"(r) : "v"(lo), "v"(hi));
  return r;
}
__device__ __forceinline__ f32x4 mfma16(bf16x8 a, bf16x8 b, f32x4 c) {
  return __builtin_amdgcn_mfma_f32_16x16x32_bf16(a, b, c, 0, 0, 0);
}
__device__ __forceinline__ f32x16 mfma32(bf16x8 a, bf16x8 b, f32x16 c) {
  return __builtin_amdgcn_mfma_f32_32x32x16_bf16(a, b, c, 0, 0, 0);
}
typedef __attribute__((address_space(3))) u32 lds_u32;
typedef const __attribute__((address_space(1))) u32 glb_u32;
__device__ __forceinline__ void gld_lds16(u16* lds, const u16* g) {
  __builtin_amdgcn_global_load_lds((glb_u32*)g, (lds_u32*)lds, 16, 0, 0);
}
__device__ __forceinline__ bf16x8 ld_bf8(const u16* p) {
  return *(const bf16x8*)p;
}

// ---------------------------------------------------------------------------
// fused f32 -> bf16 conversion for x + 4 weight matrices (8 elems/thread)
// ---------------------------------------------------------------------------
__global__ __launch_bounds__(256) void cvt_all(
    const float* __restrict__ x,
    const float* __restrict__ Wq, const float* __restrict__ Wk,
    const float* __restrict__ Wv, const float* __restrict__ Wo,
    u16* __restrict__ xb, u16* __restrict__ Wqb, u16* __restrict__ Wkb,
    u16* __restrict__ Wvb, u16* __restrict__ Wob) {
  const size_t i = (size_t)(blockIdx.x * 256 + threadIdx.x) * 8;
  const float* s; u16* d; size_t off;
  if      (i <  8388608) { s = x;  d = xb;  off = i; }
  else if (i <  9437184) { s = Wq; d = Wqb; off = i -  8388608; }
  else if (i < 10485760) { s = Wk; d = Wkb; off = i -  9437184; }
  else if (i < 11534336) { s = Wv; d = Wvb; off = i - 10485760; }
  else                   { s = Wo; d = Wob; off = i - 11534336; }
  const float4* sp = (const float4*)(s + off);
  float4 a = sp[0], b = sp[1];
  u16 r[8];
  r[0] = f2bf(a.x); r[1] = f2bf(a.y); r[2] = f2bf(a.z); r[3] = f2bf(a.w);
  r[4] = f2bf(b.x); r[5] = f2bf(b.y); r[6] = f2bf(b.z); r[7] = f2bf(b.w);
  *(uint4*)(d + off) = *(const uint4*)r;
}

// ---------------------------------------------------------------------------
// mask [S][S] f32 -> maskT [k][q] bf16 (transposed), 32x32 LDS tiles
// (KEPT as separate kernel: the transpose is semantically required — R9's
//  fused version dropped it and broke both outputs.)
// ---------------------------------------------------------------------------
__global__ __launch_bounds__(256) void trans_mask(
    const float* __restrict__ m, u16* __restrict__ mt) {
  __shared__ u16 L[32][33];
  const int x = threadIdx.x & 31, y4 = threadIdx.x >> 5;   // y4: 0..7
  const int r0 = blockIdx.y * 32, c0 = blockIdx.x * 32;
#pragma unroll
  for (int j = 0; j < 4; ++j) {
    const int r = y4 * 4 + j;
    L[x][r] = f2bf(m[(r0 + r) * 1024 + c0 + x]);
  }
  __syncthreads();
#pragma unroll
  for (int j = 0; j < 4; ++j) {
    const int rr = y4 * 4 + j;
    mt[(c0 + rr) * 1024 + r0 + x] = L[rr][x];
  }
}

// ---------------------------------------------------------------------------
// maskT [k][q] -> maskP [c][hi][q][r:16]  (MFMA-fragment-ordered mask)
// ---------------------------------------------------------------------------
__global__ __launch_bounds__(256) void mask_pack(
    const u16* __restrict__ mt, u16* __restrict__ mp) {
  const int id = blockIdx.x * 256 + threadIdx.x;   // 65536 threads
  const int q  = id & 1023;
  const int hi = (id >> 10) & 1;
  const int c  = id >> 11;
  u16 r0[8], r1[8];
#pragma unroll
  for (int r = 0; r < 8; ++r)
    r0[r] = mt[(32 * c + (r & 3) + 8 * (r >> 2) + 4 * hi) * 1024 + q];
#pragma unroll
  for (int r = 8; r < 16; ++r)
    r1[r - 8] = mt[(32 * c + (r & 3) + 8 * (r >> 2) + 4 * hi) * 1024 + q];
  u16* dst = mp + ((size_t)((c * 2 + hi) * 1024 + q)) * 16;
  *(uint4*)dst       = *(const uint4*)r0;
  *(uint4*)(dst + 8) = *(const uint4*)r1;
}

// ---------------------------------------------------------------------------
// Projection GEMM: C[8192, 3072] = xb @ [Wq;Wk;Wv]^T  (K=1024, BK=32, 128x128)
// 2-phase pipelined (double-buffered LDS, stage-next before compute).
// REGULAR epilogue stores (scattered 2B/8B rely on L2 write-coalescing;
// NT here was R14's −56 µs regression).
//   region 0 -> Qt2 = (C+bq)*scale  [bh][g=d>>3][s][e=d&7] bf16
//   region 1 -> Kt2 = C*scale       [bh][g=d>>3][s][e=d&7] bf16
//   region 2 -> V2  = C+bv          [bh][s>>3][d][s&7]     bf16
// ---------------------------------------------------------------------------
__global__ __launch_bounds__(256) void proj_gemm(
    const u16* __restrict__ xb,
    const u16* __restrict__ Wqb, const u16* __restrict__ Wkb,
    const u16* __restrict__ Wvb,
    const float* __restrict__ bq, const float* __restrict__ bv,
    u16* __restrict__ Qt2, u16* __restrict__ Kt2, u16* __restrict__ V2) {
  __shared__ u16 As[2][128][32];
  __shared__ u16 Bs[2][128][32];
  const int tid  = threadIdx.x;
  const int lane = tid & 63;
  const int wid  = tid >> 6;
  const int c15  = lane & 15, c4 = lane >> 4;
  const int m0   = blockIdx.x * 128;
  const int nv0  = blockIdx.y * 128;          // virtual col in [0,3072)
  const int region = nv0 >> 10;               // 0=q 1=k 2=v (1024-aligned)
  const int nl0  = nv0 & 1023;
  const u16* Wsrc = (region == 0) ? Wqb : (region == 1) ? Wkb : Wvb;
  const int wrow = wid >> 1, wcol = wid & 1;
  const int srow = lane >> 2, scol = (lane & 3) * 8;

  const u16* aptr = xb   + (m0  + srow) * 1024 + scol;
  const u16* bptr = Wsrc + (nl0 + srow) * 1024 + scol;

  f32x4 acc[4][4] = {};

#pragma unroll
  for (int j = 0; j < 2; ++j) {
    const int r = 64 * j + 16 * wid;
    gld_lds16(&As[0][r][0], aptr + r * 1024);
    gld_lds16(&Bs[0][r][0], bptr + r * 1024);
  }
  __syncthreads();

  int cur = 0;
  for (int k0 = 0; k0 < 1024; k0 += 32) {
    if (k0 + 32 < 1024) {
      const int nxt = cur ^ 1;
#pragma unroll
      for (int j = 0; j < 2; ++j) {
        const int r = 64 * j + 16 * wid;
        gld_lds16(&As[nxt][r][0], aptr + r * 1024 + k0 + 32);
        gld_lds16(&Bs[nxt][r][0], bptr + r * 1024 + k0 + 32);
      }
    }
    bf16x8 af[4], bfr[4];
#pragma unroll
    for (int a = 0; a < 4; ++a) af[a]  = ld_bf8(&As[cur][64 * wrow + 16 * a + c15][8 * c4]);
#pragma unroll
    for (int b = 0; b < 4; ++b) bfr[b] = ld_bf8(&Bs[cur][64 * wcol + 16 * b + c15][8 * c4]);
#pragma unroll
    for (int a = 0; a < 4; ++a)
#pragma unroll
      for (int b = 0; b < 4; ++b)
        acc[a][b] = mfma16(af[a], bfr[b], acc[a][b]);
    __syncthreads();
    cur ^= 1;
  }

  const float kSc = 0.35355339059327373f;  // 64^-0.25
#pragma unroll
  for (int a = 0; a < 4; ++a) {
    const int mg = m0 + 64 * wrow + 16 * a + 4 * c4;
    const int bb = mg >> 10;                 // batch
    const int sl = mg & 1023;                // seq pos (mg%4==0, j adds 0..3)
#pragma unroll
    for (int b = 0; b < 4; ++b) {
      const int nl = 64 * wcol + 16 * b + c15;
      const int nv = nv0 + nl;
      if (region == 0) {
        const int n = nv;                    // h*64 + d
        const float bias = bq[n];
        u16* qp = Qt2 + (((bb * 16 + (n >> 6)) * 8 + ((n >> 3) & 7)) * 1024 + sl) * 8 + (n & 7);
#pragma unroll
        for (int j = 0; j < 4; ++j)
          qp[j * 8] = f2bf((acc[a][b][j] + bias) * kSc);
      } else if (region == 1) {
        const int n = nv - 1024;             // h*64 + d
        u16* kp = Kt2 + (((bb * 16 + (n >> 6)) * 8 + ((n >> 3) & 7)) * 1024 + sl) * 8 + (n & 7);
#pragma unroll
        for (int j = 0; j < 4; ++j)
          kp[j * 8] = f2bf(acc[a][b][j] * kSc);
      } else {
        const int n = nv - 2048;             // h*64 + d
        const float bias = bv[n];
        u16* vp = V2 + (((bb * 16 + (n >> 6)) * 128 + (sl >> 3)) * 64 + (n & 63)) * 8 + (sl & 7);
        u16 p[4];
#pragma unroll
        for (int j = 0; j < 4; ++j) p[j] = f2bf(acc[a][b][j] + bias);
        *(uint2*)vp = *(const uint2*)p;      // 4 consecutive s, 8B store
      }
    }
  }
}

// ---------------------------------------------------------------------------
// Attention v6: single-pass online softmax (defer-max), swapped QK^T,
// loads issued before qk stores (vmcnt decoupling, R7 win),
// NON-TEMPORAL qk stores (L2-thrash fix, R12 win),
// cvt_pk P-pack + max3 tree + dual-l (R10).
// ---------------------------------------------------------------------------
__global__ __launch_bounds__(256) void attn_v6(
    const u16* __restrict__ Qt2, const u16* __restrict__ Kt2,
    const u16* __restrict__ V2, const u16* __restrict__ maskP,
    float* __restrict__ qk, u16* __restrict__ WV) {
  __shared__ float Tb[4][32 * 34];
  __shared__ float invl[4][32];
  __shared__ float factw[4][32];
  const int tid  = threadIdx.x;
  const int lane = tid & 63;
  const int w    = tid >> 6;
  const int r31  = lane & 31, hi = lane >> 5;
  const int h = blockIdx.y, b = blockIdx.z;
  const int bh  = b * 16 + h;
  const int q0  = blockIdx.x * 128 + w * 32;
  const int bs0 = b * 1024;

  const u16* qbase = Qt2 + (size_t)bh * 65536;
  const u16* kbase = Kt2 + (size_t)bh * 65536;
  const u16* vbase = V2  + (size_t)bh * 65536;
  float* Tw = Tb[w];
  float* qkbase = qk + ((size_t)bh * 1024 + q0) * 1024;

  bf16x8 qf[4];
#pragma unroll
  for (int kk = 0; kk < 4; ++kk)
    qf[kk] = ld_bf8(qbase + ((2 * kk + hi) * 1024 + q0 + r31) * 8);

  const u16* mrow = maskP + ((size_t)(hi * 1024 + q0 + r31)) * 16;

  float m_run = -3e38f;
  float l0 = 0.f, l1 = 0.f;
  f32x16 oa0 = {}, oa1 = {};

  bf16x8 kc[4];
#pragma unroll
  for (int kk = 0; kk < 4; ++kk)
    kc[kk] = ld_bf8(kbase + ((2 * kk + hi) * 1024 + r31) * 8);
  bf16x8 mc0 = ld_bf8(mrow);
  bf16x8 mc1 = ld_bf8(mrow + 8);

  for (int c = 0; c < 32; ++c) {
    // ---- loads consumed this iter / next iter: ISSUED BEFORE qk stores ----
    bf16x8 vf[4];
#pragma unroll
    for (int kk = 0; kk < 2; ++kk) {
      const int sb = 4 * c + 2 * kk + hi;
      vf[2 * kk]     = ld_bf8(vbase + (sb * 64 + r31) * 8);
      vf[2 * kk + 1] = ld_bf8(vbase + (sb * 64 + 32 + r31) * 8);
    }
    const int cn = (c < 31) ? c + 1 : 31;
    bf16x8 kn[4];
#pragma unroll
    for (int kk = 0; kk < 4; ++kk)
      kn[kk] = ld_bf8(kbase + ((2 * kk + hi) * 1024 + 32 * cn + r31) * 8);
    bf16x8 mn0 = ld_bf8(mrow + (size_t)cn * 32768);
    bf16x8 mn1 = ld_bf8(mrow + (size_t)cn * 32768 + 8);

    // ---- QK^T tile: S[32k][32q], lane col = q ----
    f32x16 acc = {};
#pragma unroll
    for (int kk = 0; kk < 4; ++kk)
      acc = mfma32(kc[kk], qf[kk], acc);

    float v[16];
    const u16* mcu0 = (const u16*)&mc0;
    const u16* mcu1 = (const u16*)&mc1;
#pragma unroll
    for (int r = 0; r < 16; ++r)
      v[r] = acc[r] + bf2f(r < 8 ? mcu0[r] : mcu1[r - 8]);
    // max3-fusable reduction tree
    float t0 = fmaxf(fmaxf(v[0], v[1]),  v[2]);
    float t1 = fmaxf(fmaxf(v[3], v[4]),  v[5]);
    float t2 = fmaxf(fmaxf(v[6], v[7]),  v[8]);
    float t3 = fmaxf(fmaxf(v[9], v[10]), v[11]);
    float t4 = fmaxf(fmaxf(v[12], v[13]), v[14]);
    float mloc = fmaxf(fmaxf(fmaxf(fmaxf(t0, t1), t2), fmaxf(t3, t4)), v[15]);
    mloc = fmaxf(mloc, __shfl_xor(mloc, 32));

    // ---- park S in Tw (float2-packed; kr = 8g+4hi+j) ----
#pragma unroll
    for (int g = 0; g < 4; ++g) {
      float2 w0; w0.x = v[4 * g];     w0.y = v[4 * g + 1];
      float2 w1; w1.x = v[4 * g + 2]; w1.y = v[4 * g + 3];
      *(float2*)&Tw[r31 * 34 + 8 * g + 4 * hi]     = w0;
      *(float2*)&Tw[r31 * 34 + 8 * g + 4 * hi + 2] = w1;
    }

    // ---- defer-max rescale (rare) ----
    if (!__all(mloc <= m_run + 8.f)) {
      const float m_new = fmaxf(m_run, mloc);
      const float f = __expf(m_run - m_new);
      l0 *= f; l1 *= f;
      if (hi == 0) factw[w][r31] = f;
      asm volatile("s_waitcnt lgkmcnt(0)" ::: "memory");
#pragma unroll
      for (int r = 0; r < 16; ++r) {
        const float fr_ = factw[w][(r & 3) + 8 * (r >> 2) + 4 * hi];
        oa0[r] *= fr_;
        oa1[r] *= fr_;
      }
      m_run = m_new;
    }

    // ---- readback transposed rows -> 128B-coalesced NT qk stores ----
#pragma unroll
    for (int qi = 0; qi < 4; ++qi) {
      const int qq = 8 * qi + (lane >> 3);
      const int jj = (lane & 7) * 4;
      float2 u0 = *(const float2*)&Tw[qq * 34 + jj];
      float2 u1 = *(const float2*)&Tw[qq * 34 + jj + 2];
      f32x4 o; o[0] = u0.x; o[1] = u0.y; o[2] = u1.x; o[3] = u1.y;
      __builtin_nontemporal_store(o, (f32x4*)&qkbase[qq * 1024 + 32 * c + jj]);
    }

    // ---- P = exp(S - m_run), l accumulate (2 chains) ----
#pragma unroll
    for (int r = 0; r < 16; ++r)
      v[r] = __expf(v[r] - m_run);
#pragma unroll
    for (int r = 0; r < 8; ++r) { l0 += v[2 * r]; l1 += v[2 * r + 1]; }

    // ---- PV: build A-frags via cvt_pk + half-exchange ----
#pragma unroll
    for (int kk = 0; kk < 2; ++kk) {
      const float* pp = v + 8 * kk;
      const u32 a0 = cvtpk(pp[0], pp[1]), a1 = cvtpk(pp[2], pp[3]);
      const u32 b0 = cvtpk(pp[4], pp[5]), b1 = cvtpk(pp[6], pp[7]);
      const u32 s0 = hi ? a0 : b0, s1 = hi ? a1 : b1;
      const u32 t0x = __shfl_xor(s0, 32), t1x = __shfl_xor(s1, 32);
      union { u32 u[4]; bf16x8 v; } fr;
      fr.u[0] = hi ? t0x : a0;  fr.u[1] = hi ? t1x : a1;
      fr.u[2] = hi ? b0 : t0x;  fr.u[3] = hi ? b1 : t1x;
      oa0 = mfma32(fr.v, vf[2 * kk],     oa0);
      oa1 = mfma32(fr.v, vf[2 * kk + 1], oa1);
    }

#pragma unroll
    for (int kk = 0; kk < 4; ++kk) kc[kk] = kn[kk];
    mc0 = mn0; mc1 = mn1;
  }

  float l = l0 + l1;
  l += __shfl_xor(l, 32);
  if (hi == 0) invl[w][r31] = 1.0f / l;
  asm volatile("s_waitcnt lgkmcnt(0)" ::: "memory");
#pragma unroll
  for (int r = 0; r < 16; ++r) {
    const int q = (r & 3) + 8 * (r >> 2) + 4 * hi;
    const float iv = invl[w][q];
    u16* wp = WV + (size_t)(bs0 + q0 + q) * 1024 + h * 64;
    wp[r31]      = f2bf(oa0[r] * iv);
    wp[32 + r31] = f2bf(oa1[r] * iv);
  }
}

// ---------------------------------------------------------------------------
// Output GEMM: out[8192,1024] = WV @ Wo^T + bo  (f32 out), 2-phase pipelined.
// outp stores non-temporal (coalesced full-line stream, never re-read).
// ---------------------------------------------------------------------------
__global__ __launch_bounds__(256) void out_gemm(
    const u16* __restrict__ Ab, const u16* __restrict__ Wb,
    const float* __restrict__ bias, float* __restrict__ outp) {
  __shared__ u16 As[2][128][32];
  __shared__ u16 Bs[2][128][32];
  const int tid  = threadIdx.x;
  const int lane = tid & 63;
  const int wid  = tid >> 6;
  const int c15  = lane & 15, c4 = lane >> 4;
  const int m0   = blockIdx.x * 128;
  const int n0   = blockIdx.y * 128;
  const int wrow = wid >> 1, wcol = wid & 1;
  const int srow = lane >> 2, scol = (lane & 3) * 8;

  const u16* aptr = Ab + (m0 + srow) * 1024 + scol;
  const u16* bptr = Wb + (n0 + srow) * 1024 + scol;

  f32x4 acc[4][4] = {};

#pragma unroll
  for (int j = 0; j < 2; ++j) {
    const int r = 64 * j + 16 * wid;
    gld_lds16(&As[0][r][0], aptr + r * 1024);
    gld_lds16(&Bs[0][r][0], bptr + r * 1024);
  }
  __syncthreads();

  int cur = 0;
  for (int k0 = 0; k0 < 1024; k0 += 32) {
    if (k0 + 32 < 1024) {
      const int nxt = cur ^ 1;
#pragma unroll
      for (int j = 0; j < 2; ++j) {
        const int r = 64 * j + 16 * wid;
        gld_lds16(&As[nxt][r][0], aptr + r * 1024 + k0 + 32);
        gld_lds16(&Bs[nxt][r][0], bptr + r * 1024 + k0 + 32);
      }
    }
    bf16x8 af[4], bfr[4];
#pragma unroll
    for (int a = 0; a < 4; ++a) af[a]  = ld_bf8(&As[cur][64 * wrow + 16 * a + c15][8 * c4]);
#pragma unroll
    for (int b = 0; b < 4; ++b) bfr[b] = ld_bf8(&Bs[cur][64 * wcol + 16 * b + c15][8 * c4]);
#pragma unroll
    for (int a = 0; a < 4; ++a)
#pragma unroll
      for (int b = 0; b < 4; ++b)
        acc[a][b] = mfma16(af[a], bfr[b], acc[a][b]);
    __syncthreads();
    cur ^= 1;
  }

#pragma unroll
  for (int a = 0; a < 4; ++a) {
    const int mg = m0 + 64 * wrow + 16 * a + 4 * c4;
#pragma unroll
    for (int b = 0; b < 4; ++b) {
      const int ng = n0 + 64 * wcol + 16 * b + c15;
      const float bi = bias[ng];
#pragma unroll
      for (int j = 0; j < 4; ++j)
        __builtin_nontemporal_store(acc[a][b][j] + bi,
                                    &outp[(size_t)(mg + j) * 1024 + ng]);
    }
  }
}

// ---------------------------------------------------------------------------
extern "C" void kernel_launch(void* const* d_in, const int* in_sizes, int n_in,
                              void* d_out, int out_size, void* d_ws, size_t ws_size,
                              hipStream_t stream) {
  const float* x    = (const float*)d_in[0];
  const float* mask = (const float*)d_in[1];
  const float* Wq   = (const float*)d_in[2];
  const float* bq   = (const float*)d_in[3];
  const float* Wk   = (const float*)d_in[4];
  const float* Wv   = (const float*)d_in[5];
  const float* bv   = (const float*)d_in[6];
  const float* Wo   = (const float*)d_in[7];
  const float* bo   = (const float*)d_in[8];

  float* outp = (float*)d_out;
  float* qk   = outp + 8 * 1024 * 1024;      // second output

  // workspace (bf16 elements): ~94 MB total
  u16* ws    = (u16*)d_ws;
  u16* xb    = ws;                    // 8388608
  u16* Wqb   = xb  + 8388608;         // 1048576
  u16* Wkb   = Wqb + 1048576;
  u16* Wvb   = Wkb + 1048576;
  u16* Wob   = Wvb + 1048576;
  u16* Qt2   = Wob + 1048576;         // 8388608 ([bh][d>>3][s][d&7], scaled+bias)
  u16* Kt2   = Qt2 + 8388608;         // 8388608 ([bh][d>>3][s][d&7], scaled)
  u16* V2    = Kt2 + 8388608;         // 8388608 ([bh][s>>3][d][s&7])
  u16* WV    = V2  + 8388608;         // 8388608
  u16* maskT = WV  + 8388608;         // 1048576 (bf16, transposed [k][q])
  u16* maskP = maskT + 1048576;       // 1048576 (fragment-ordered [c][hi][q][r])

  cvt_all<<<6144, 256, 0, stream>>>(x, Wq, Wk, Wv, Wo, xb, Wqb, Wkb, Wvb, Wob);
  trans_mask<<<dim3(32, 32), 256, 0, stream>>>(mask, maskT);
  mask_pack<<<256, 256, 0, stream>>>(maskT, maskP);

  proj_gemm<<<dim3(64, 24), 256, 0, stream>>>(xb, Wqb, Wkb, Wvb, bq, bv, Qt2, Kt2, V2);
  attn_v6<<<dim3(8, 16, 8), 256, 0, stream>>>(Qt2, Kt2, V2, maskP, qk, WV);
  out_gemm<<<dim3(64, 8), 256, 0, stream>>>(WV, Wob, bo, outp);
}